// Round 13
// baseline (845.273 us; speedup 1.0000x reference)
//
#include <hip/hip_runtime.h>
#include <math.h>

#define NN 100000
#define ND 1000000
#define INDIM 133
#define K1P 160                 // padded input dim (5 x 32)
#define NCNT (2*NN)
#define HS 72                   // LDS h-tile row stride in bf16 elems (144B)
#define NBLK_X (NN / 4)         // 25000 stat blocks
#define NBLK_E ((ND + 255) / 256)
#define SCAN_PER 200            // 1024 threads x 200 = 204800 >= NCNT

typedef __bf16 bf16x8 __attribute__((ext_vector_type(8)));
typedef __bf16 bf16x4 __attribute__((ext_vector_type(4)));
typedef float  f32x4  __attribute__((ext_vector_type(4)));
typedef _Float16 f16;
typedef _Float16 f16x4 __attribute__((ext_vector_type(4)));

__device__ __forceinline__ f32x4 mfma_bf16(bf16x8 a, bf16x8 b, f32x4 c) {
    return __builtin_amdgcn_mfma_f32_16x16x32_bf16(a, b, c, 0, 0, 0);
}

__device__ __forceinline__ float3 f3sub(float3 a, float3 b) {
    return make_float3(a.x - b.x, a.y - b.y, a.z - b.z);
}
__device__ __forceinline__ float3 f3cross(float3 a, float3 b) {
    return make_float3(a.y * b.z - a.z * b.y, a.z * b.x - a.x * b.z, a.x * b.y - a.y * b.x);
}
__device__ __forceinline__ float f3dot(float3 a, float3 b) {
    return a.x * b.x + a.y * b.y + a.z * b.z;
}
__device__ __forceinline__ float3 f3load(const float* __restrict__ p, int idx) {
    const float* q = p + (size_t)idx * 3;
    return make_float3(q[0], q[1], q[2]);
}
__device__ __forceinline__ float fsilu(float v) {
    return v / (1.0f + __expf(-v));
}

// ---- merged prep: weights (0..57) + per-node stats (58..58+24999) + count (rest) ----
__global__ __launch_bounds__(256) void prep_merged(
    const float* __restrict__ x,
    const float* __restrict__ w1, const float* __restrict__ b1,
    const float* __restrict__ w2,
    const float* __restrict__ w3, const float* __restrict__ b3,
    const float* __restrict__ wout,
    const float* __restrict__ gamma, const float* __restrict__ beta,
    const int* __restrict__ qidx,
    __bf16* __restrict__ w1h, __bf16* __restrict__ w1l,
    float* __restrict__ c1, float* __restrict__ d1,
    __bf16* __restrict__ w2h, __bf16* __restrict__ w2l,
    __bf16* __restrict__ w3h, __bf16* __restrict__ w3l,
    float* __restrict__ b3f,
    float2* __restrict__ sq,
    int* __restrict__ cnt)     // pre-zeroed; histogram of j (buckets 0..NN) and k (NN..2NN)
{
    const int b = blockIdx.x, tid = threadIdx.x;
    if (b < 40) {                       // w1g = diag(gamma) @ w1, [n][k] padded, hi/lo
        int idx = b * 256 + tid;        // 40*256 = 10240 = 64*160 exactly
        int n = idx / K1P, kp = idx - n * K1P;
        float v = (kp < INDIM) ? gamma[kp] * w1[(size_t)kp * 64 + n] : 0.0f;
        __bf16 h = (__bf16)v;
        w1h[idx] = h;
        w1l[idx] = (__bf16)(v - (float)h);
    } else if (b == 40) {               // c1 = gamma@w1, d1 = beta@w1 + b1
        if (tid < 64) {
            float sc = 0.0f, sd = 0.0f;
            for (int k = 0; k < INDIM; ++k) {
                float wv = w1[(size_t)k * 64 + tid];
                sc = fmaf(gamma[k], wv, sc);
                sd = fmaf(beta[k], wv, sd);
            }
            c1[tid] = sc;
            d1[tid] = sd + b1[tid];
        }
    } else if (b < 57) {                // w2 transposed [n][k'], permuted k
        int idx = (b - 41) * 256 + tid; // 16*256 = 4096
        int n = idx >> 6, kp = idx & 63;
        int ko = 16 * (kp & 3) + (kp >> 2);
        float v = w2[(size_t)ko * 64 + n];
        __bf16 h = (__bf16)v;
        w2h[idx] = h;
        w2l[idx] = (__bf16)(v - (float)h);
    } else if (b == 57) {               // w3'' = (w3 @ wout) * 2^-4, [c][k'] permuted
        for (int idx = tid; idx < 64 * 64; idx += 256) {
            int k = idx >> 6, c = idx & 63;
            float s = 0.0f;
            for (int q = 0; q < 64; ++q)
                s = fmaf(w3[(size_t)k * 64 + q], wout[(size_t)q * 64 + c], s);
            s *= 0.0625f;
            __bf16 h = (__bf16)s;
            int kp = 4 * (k & 15) + (k >> 4);
            w3h[(size_t)c * 64 + kp] = h;
            w3l[(size_t)c * 64 + kp] = (__bf16)(s - (float)h);
        }
        if (tid < 64) {
            float s = 0.0f;
            for (int q = 0; q < 64; ++q)
                s = fmaf(b3[q], wout[(size_t)q * 64 + tid], s);
            b3f[tid] = s * 0.0625f;
        }
    } else if (b < 58 + NBLK_X) {       // per-node LN stats
        const int n = (b - 58) * 4 + (tid >> 6);
        const int c = tid & 63;
        float v = x[(size_t)n * 64 + c];
        float s = v, q = v * v;
#pragma unroll
        for (int d = 1; d < 64; d <<= 1) {
            s += __shfl_xor(s, d);
            q += __shfl_xor(q, d);
        }
        if (c == 0) sq[n] = make_float2(s, q);
    } else {                            // degree histogram (j then k)
        int e = (b - 58 - NBLK_X) * 256 + tid;
        if (e < ND) {
            atomicAdd(&cnt[qidx[ND + e]], 1);
            atomicAdd(&cnt[NN + qidx[2 * ND + e]], 1);
        }
    }
}

// ---- single-launch global exclusive scan of off[0..NCNT) (one 1024-thread block) ----
__global__ __launch_bounds__(1024) void scan_all(int* __restrict__ off) {
    __shared__ int lds[1024];
    const int tid = threadIdx.x;
    const int base = tid * SCAN_PER;
    int tsum = 0;
    for (int i = 0; i < SCAN_PER; ++i) {
        int idx = base + i;
        if (idx < NCNT) tsum += off[idx];
    }
    lds[tid] = tsum;
    __syncthreads();
    for (int d = 1; d < 1024; d <<= 1) {
        int u = (tid >= d) ? lds[tid - d] : 0;
        __syncthreads();
        lds[tid] += u;
        __syncthreads();
    }
    int run = lds[tid] - tsum;   // exclusive prefix of this thread's chunk
    for (int i = 0; i < SCAN_PER; ++i) {
        int idx = base + i;
        if (idx < NCNT) {
            int v = off[idx];
            off[idx] = run;
            run += v;
        }
    }
}

// ---- edge MLP: R12 body + s_setprio around the pure-MFMA clusters (T5) ----
__global__ __launch_bounds__(256, 3) void edge_mlp_mfma(
    const float* __restrict__ x,
    const float2* __restrict__ sq,
    const float* __restrict__ pos,
    const int* __restrict__ qidx, const float* __restrict__ qattr,
    const __bf16* __restrict__ w1h, const __bf16* __restrict__ w1l,
    const float* __restrict__ c1, const float* __restrict__ d1,
    const __bf16* __restrict__ w2h, const __bf16* __restrict__ w2l, const float* __restrict__ b2,
    const __bf16* __restrict__ w3h, const __bf16* __restrict__ w3l, const float* __restrict__ b3f,
    int* __restrict__ off,        // global bucket cursors (post-scan); mutated to bucket ends
    f16* __restrict__ msg)
{
    __shared__ __align__(16) __bf16 hsh[4][4][16 * HS];   // 36 KB

    const int tid = threadIdx.x;
    const int w   = tid >> 6;
    const int l   = tid & 63;
    const int m   = l & 15;
    const int kg  = l >> 4;
    const int ebase = (blockIdx.x * 4 + w) * 64;
    if (ebase >= ND) return;               // no barriers: early-out safe

    // ---- slot acquisition: one edge per lane, issued first so the atomic
    // round-trip hides under the whole MFMA body ----
    int vj, vk;
    {
        const int me = ebase + l;
        vj = atomicAdd(&off[qidx[ND + me]], 1);
        vk = atomicAdd(&off[NN + qidx[2 * ND + me]], 1);
    }

    int iA[4], lA[4];
#pragma unroll
    for (int t = 0; t < 4; ++t) {
        const int e = ebase + 16 * t + m;
        iA[t] = qidx[e];
        lA[t] = qidx[3 * ND + e];
    }

    // ---- dihedral + raw-extras: lane handles tile kg, edge m (all 64 lanes busy) ----
    float cosd, sind, at0, at1, at2, se, qe;
    {
        const int e2 = ebase + 16 * kg + m;
        const int i2 = qidx[e2];
        const int j2 = qidx[ND + e2];
        const int k2 = qidx[2 * ND + e2];
        const int l2 = qidx[3 * ND + e2];
        float3 pi = f3load(pos, i2), pj = f3load(pos, j2);
        float3 pk = f3load(pos, k2), pl = f3load(pos, l2);
        float3 d1v_ = f3sub(pj, pi);
        float3 d2v_ = f3sub(pk, pj);
        float3 d3v_ = f3sub(pl, pk);
        float3 n1 = f3cross(d1v_, d2v_);
        float3 n2 = f3cross(d2v_, d3v_);
        float r1 = 1.0f / fmaxf(sqrtf(f3dot(n1, n1)), 1e-6f);
        n1.x *= r1; n1.y *= r1; n1.z *= r1;
        float r2 = 1.0f / fmaxf(sqrtf(f3dot(n2, n2)), 1e-6f);
        n2.x *= r2; n2.y *= r2; n2.z *= r2;
        cosd = fminf(fmaxf(f3dot(n1, n2), -1.0f), 1.0f);
        float rb = 1.0f / fmaxf(sqrtf(f3dot(d2v_, d2v_)), 1e-6f);
        float3 b2n = make_float3(d2v_.x * rb, d2v_.y * rb, d2v_.z * rb);
        float3 mm = f3cross(n1, b2n);
        sind = f3dot(mm, n2);
        at0 = qattr[(size_t)e2 * 3 + 0];
        at1 = qattr[(size_t)e2 * 3 + 1];
        at2 = qattr[(size_t)e2 * 3 + 2];
        se = at0 + at1 + at2 + cosd + sind;
        qe = at0 * at0 + at1 * at1 + at2 * at2 + cosd * cosd + sind * sind;
    }

    bf16x8 ah4[4], al4[4];
    float rs_[4], mn_[4];
#pragma unroll
    for (int t = 0; t < 4; ++t) {
        const int src = m + 16 * t;
        float u4[8] = {__shfl(at0, src), __shfl(at1, src), __shfl(at2, src),
                       __shfl(cosd, src), __shfl(sind, src), 0.f, 0.f, 0.f};
        float g0 = (kg == 0) ? 1.0f : 0.0f;
#pragma unroll
        for (int j = 0; j < 8; ++j) {
            float v = u4[j] * g0;
            __bf16 h = (__bf16)v;
            ah4[t][j] = h;
            al4[t][j] = (__bf16)(v - (float)h);
        }
        float2 si = sq[iA[t]], sl = sq[lA[t]];
        float S = si.x + sl.x + __shfl(se, src);
        float Q = si.y + sl.y + __shfl(qe, src);
        float mu  = S * (1.0f / INDIM);
        float var = Q * (1.0f / INDIM) - mu * mu;
        float rsv = rsqrtf(fmaxf(var, 0.0f) + 1e-5f);
        rs_[t] = rsv;
        mn_[t] = -mu * rsv;
    }

    // ---- layer 1: P = raw_x @ w1g (+ extras), split 3-MFMA ----
    f32x4 acc[4][4];
#pragma unroll
    for (int t = 0; t < 4; ++t)
#pragma unroll
        for (int nt = 0; nt < 4; ++nt) acc[t][nt] = (f32x4){0.f, 0.f, 0.f, 0.f};

    __builtin_amdgcn_s_setprio(1);
#pragma unroll
    for (int nt = 0; nt < 4; ++nt) {
        const size_t wb = (size_t)(16 * nt + m) * K1P + 128 + 8 * kg;
        bf16x8 bh = *(const bf16x8*)(w1h + wb);
        bf16x8 bl = *(const bf16x8*)(w1l + wb);
#pragma unroll
        for (int t = 0; t < 4; ++t) {
            acc[t][nt] = mfma_bf16(ah4[t], bh, acc[t][nt]);
            acc[t][nt] = mfma_bf16(al4[t], bh, acc[t][nt]);
            acc[t][nt] = mfma_bf16(ah4[t], bl, acc[t][nt]);
        }
    }
    __builtin_amdgcn_s_setprio(0);

#pragma unroll
    for (int s = 0; s < 4; ++s) {
        const int colo = 32 * (s & 1) + 8 * kg;
        bf16x8 ath[4], atl[4];
#pragma unroll
        for (int t = 0; t < 4; ++t) {
            const int r_ = (s < 2) ? iA[t] : lA[t];
            float vv[8];
            *(float4*)&vv[0] = *(const float4*)(x + (size_t)r_ * 64 + colo);
            *(float4*)&vv[4] = *(const float4*)(x + (size_t)r_ * 64 + colo + 4);
#pragma unroll
            for (int j = 0; j < 8; ++j) {
                float v = vv[j];
                __bf16 h = (__bf16)v;
                ath[t][j] = h;
                atl[t][j] = (__bf16)(v - (float)h);
            }
        }
        __builtin_amdgcn_s_setprio(1);
#pragma unroll
        for (int nt = 0; nt < 4; ++nt) {
            const size_t wb = (size_t)(16 * nt + m) * K1P + 32 * s + 8 * kg;
            bf16x8 bh = *(const bf16x8*)(w1h + wb);
            bf16x8 bl = *(const bf16x8*)(w1l + wb);
#pragma unroll
            for (int t = 0; t < 4; ++t) {
                acc[t][nt] = mfma_bf16(ath[t], bh, acc[t][nt]);
                acc[t][nt] = mfma_bf16(atl[t], bh, acc[t][nt]);
                acc[t][nt] = mfma_bf16(ath[t], bl, acc[t][nt]);
            }
        }
        __builtin_amdgcn_s_setprio(0);
    }

    // epilogue 1: h1 = silu(rs*P + (-rs*mu)*c1 + d1), permuted-col 8B LDS stores
    float c1v[4], d1v[4], b2v[4], b3v[4];
#pragma unroll
    for (int nt = 0; nt < 4; ++nt) {
        c1v[nt] = c1[16 * nt + m];
        d1v[nt] = d1[16 * nt + m];
        b2v[nt] = b2[16 * nt + m];
        b3v[nt] = b3f[16 * nt + m];
    }
#pragma unroll
    for (int t = 0; t < 4; ++t) {
        __bf16* hhw = &hsh[w][t][0];
#pragma unroll
        for (int r = 0; r < 4; ++r) {
            float rse = __shfl(rs_[t], 4 * kg + r);
            float mne = __shfl(mn_[t], 4 * kg + r);
            bf16x4 hv4;
#pragma unroll
            for (int nt = 0; nt < 4; ++nt)
                hv4[nt] = (__bf16)fsilu(fmaf(rse, acc[t][nt][r],
                                        fmaf(mne, c1v[nt], d1v[nt])));
            *(bf16x4*)(hhw + (4 * kg + r) * HS + m * 4) = hv4;
        }
    }

    // ---- layer 2: hi-A x split-W ----
    bf16x8 a2h[4][2];
#pragma unroll
    for (int t = 0; t < 4; ++t)
#pragma unroll
        for (int s = 0; s < 2; ++s)
            a2h[t][s] = *(const bf16x8*)(&hsh[w][t][m * HS + 32 * s + 8 * kg]);
    f32x4 acc2[4][4];
#pragma unroll
    for (int t = 0; t < 4; ++t)
#pragma unroll
        for (int nt = 0; nt < 4; ++nt) acc2[t][nt] = (f32x4){0.f, 0.f, 0.f, 0.f};
    __builtin_amdgcn_s_setprio(1);
#pragma unroll
    for (int s = 0; s < 2; ++s) {
#pragma unroll
        for (int nt = 0; nt < 4; ++nt) {
            const size_t wb = (size_t)(16 * nt + m) * 64 + 32 * s + 8 * kg;
            bf16x8 bh = *(const bf16x8*)(w2h + wb);
            bf16x8 bl = *(const bf16x8*)(w2l + wb);
#pragma unroll
            for (int t = 0; t < 4; ++t) {
                acc2[t][nt] = mfma_bf16(a2h[t][s], bh, acc2[t][nt]);
                acc2[t][nt] = mfma_bf16(a2h[t][s], bl, acc2[t][nt]);
            }
        }
    }
    __builtin_amdgcn_s_setprio(0);
#pragma unroll
    for (int t = 0; t < 4; ++t) {
        __bf16* hhw = &hsh[w][t][0];
#pragma unroll
        for (int r = 0; r < 4; ++r) {
            bf16x4 hv4;
#pragma unroll
            for (int nt = 0; nt < 4; ++nt)
                hv4[nt] = (__bf16)fsilu(acc2[t][nt][r] + b2v[nt]);
            *(bf16x4*)(hhw + (4 * kg + r) * HS + m * 4) = hv4;
        }
    }

    // ---- layer 3 (w_out + scale folded) ----
    bf16x8 a3h[4][2];
#pragma unroll
    for (int t = 0; t < 4; ++t)
#pragma unroll
        for (int s = 0; s < 2; ++s)
            a3h[t][s] = *(const bf16x8*)(&hsh[w][t][m * HS + 32 * s + 8 * kg]);
    f32x4 acc3[4][4];
#pragma unroll
    for (int t = 0; t < 4; ++t)
#pragma unroll
        for (int nt = 0; nt < 4; ++nt) acc3[t][nt] = (f32x4){0.f, 0.f, 0.f, 0.f};
    __builtin_amdgcn_s_setprio(1);
#pragma unroll
    for (int s = 0; s < 2; ++s) {
#pragma unroll
        for (int nt = 0; nt < 4; ++nt) {
            const size_t wb = (size_t)(16 * nt + m) * 64 + 32 * s + 8 * kg;
            bf16x8 bh = *(const bf16x8*)(w3h + wb);
            bf16x8 bl = *(const bf16x8*)(w3l + wb);
#pragma unroll
            for (int t = 0; t < 4; ++t) {
                acc3[t][nt] = mfma_bf16(a3h[t][s], bh, acc3[t][nt]);
                acc3[t][nt] = mfma_bf16(a3h[t][s], bl, acc3[t][nt]);
            }
        }
    }
    __builtin_amdgcn_s_setprio(0);

    // ---- msg: f16x4 stores to BOTH sorted slots; slot of edge er lives in
    // lane er-ebase = 16t+4kg+r (per-lane shfl src) ----
#pragma unroll
    for (int t = 0; t < 4; ++t) {
#pragma unroll
        for (int r = 0; r < 4; ++r) {
            f16x4 v;
#pragma unroll
            for (int nt = 0; nt < 4; ++nt)
                v[nt] = (f16)(acc3[t][nt][r] + b3v[nt]);
            const int src = 16 * t + 4 * kg + r;
            const int sjv = __shfl(vj, src);
            const int skv = __shfl(vk, src);
            *(f16x4*)(msg + (size_t)sjv * 64 + m * 4) = v;
            *(f16x4*)(msg + (size_t)skv * 64 + m * 4) = v;
        }
    }
}

// ---- node aggregation: R8-proven whole-wave form (uniform bounds, shfl reduce) ----
__global__ __launch_bounds__(256) void node_out(const f16* __restrict__ msg,
                                                const int* __restrict__ off,
                                                float* __restrict__ out) {
    const int w   = threadIdx.x >> 6;
    const int l   = threadIdx.x & 63;
    const int sub = l >> 4;      // row-within-4-chunk
    const int m16 = l & 15;      // permuted col group: cols' 4*m16..+3
    for (int n = blockIdx.x * 4 + w; n < NN; n += gridDim.x * 4) {
        int ja = (n == 0) ? 0 : off[n - 1];
        int jb = off[n];
        int ka = off[NN + n - 1];   // n==0 -> off[NN-1] = start of k-region
        int kb = off[NN + n];
        float s0 = 0.f, s1 = 0.f, s2 = 0.f, s3 = 0.f;
        float t0 = 0.f, t1 = 0.f, t2 = 0.f, t3 = 0.f;
        for (int p = ja + sub; p < jb; p += 4) {
            f16x4 v = *(const f16x4*)(msg + (size_t)p * 64 + m16 * 4);
            s0 += (float)v[0]; s1 += (float)v[1];
            s2 += (float)v[2]; s3 += (float)v[3];
        }
        for (int p = ka + sub; p < kb; p += 4) {
            f16x4 v = *(const f16x4*)(msg + (size_t)p * 64 + m16 * 4);
            t0 += (float)v[0]; t1 += (float)v[1];
            t2 += (float)v[2]; t3 += (float)v[3];
        }
        s0 += __shfl_xor(s0, 16); s0 += __shfl_xor(s0, 32);
        s1 += __shfl_xor(s1, 16); s1 += __shfl_xor(s1, 32);
        s2 += __shfl_xor(s2, 16); s2 += __shfl_xor(s2, 32);
        s3 += __shfl_xor(s3, 16); s3 += __shfl_xor(s3, 32);
        t0 += __shfl_xor(t0, 16); t0 += __shfl_xor(t0, 32);
        t1 += __shfl_xor(t1, 16); t1 += __shfl_xor(t1, 32);
        t2 += __shfl_xor(t2, 16); t2 += __shfl_xor(t2, 32);
        t3 += __shfl_xor(t3, 16); t3 += __shfl_xor(t3, 32);
        if (sub == 0) {
            float rj = 1.0f / fmaxf((float)(jb - ja), 1.0f);
            float rk = 1.0f / fmaxf((float)(kb - ka), 1.0f);
            float* o = out + (size_t)n * 64;
            o[m16]      = s0 * rj + t0 * rk;   // col' 4m+nt <-> true col 16nt+m
            o[16 + m16] = s1 * rj + t1 * rk;
            o[32 + m16] = s2 * rj + t2 * rk;
            o[48 + m16] = s3 * rj + t3 * rk;
        }
    }
}

// ============================ launch ============================

extern "C" void kernel_launch(void* const* d_in, const int* in_sizes, int n_in,
                              void* d_out, int out_size, void* d_ws, size_t ws_size,
                              hipStream_t stream) {
    (void)in_sizes; (void)n_in; (void)out_size;

    const float* x     = (const float*)d_in[0];
    const float* pos   = (const float*)d_in[1];
    const int*   qidx  = (const int*)d_in[2];
    const float* qattr = (const float*)d_in[3];
    const float* gamma = (const float*)d_in[4];
    const float* beta  = (const float*)d_in[5];
    const float* w1    = (const float*)d_in[6];
    const float* b1    = (const float*)d_in[7];
    const float* w2    = (const float*)d_in[8];
    const float* b2    = (const float*)d_in[9];
    const float* w3    = (const float*)d_in[10];
    const float* b3    = (const float*)d_in[11];
    const float* w_out = (const float*)d_in[12];
    float* out = (float*)d_out;

    size_t o = 0;
    auto alloc = [&](size_t bytes) { size_t r = o; o = (o + bytes + 255) & ~(size_t)255; return r; };
    char* W = (char*)d_ws;
    f16*    msg    = (f16*)   (W + alloc((size_t)2 * ND * 64 * sizeof(f16)));   // 244 MiB
    int*    off    = (int*)   (W + alloc((size_t)NCNT * sizeof(int)));
    float2* sqt    = (float2*)(W + alloc((size_t)NN * sizeof(float2)));
    __bf16* w1h    = (__bf16*)(W + alloc((size_t)64 * K1P * sizeof(__bf16)));
    __bf16* w1l    = (__bf16*)(W + alloc((size_t)64 * K1P * sizeof(__bf16)));
    __bf16* w2h    = (__bf16*)(W + alloc((size_t)64 * 64 * sizeof(__bf16)));
    __bf16* w2l    = (__bf16*)(W + alloc((size_t)64 * 64 * sizeof(__bf16)));
    __bf16* w3h    = (__bf16*)(W + alloc((size_t)64 * 64 * sizeof(__bf16)));
    __bf16* w3l    = (__bf16*)(W + alloc((size_t)64 * 64 * sizeof(__bf16)));
    float*  c1     = (float*) (W + alloc((size_t)64 * sizeof(float)));
    float*  d1     = (float*) (W + alloc((size_t)64 * sizeof(float)));
    float*  b3f    = (float*) (W + alloc((size_t)64 * sizeof(float)));
    if (ws_size < o) return;   // ~245 MiB — well within proven ws bound

    // zero histogram, then merged prep (weights + stats + count in ONE launch)
    hipMemsetAsync(off, 0, (size_t)NCNT * sizeof(int), stream);
    prep_merged<<<58 + NBLK_X + NBLK_E, 256, 0, stream>>>(
        x, w1, b1, w2, w3, b3, w_out, gamma, beta, qidx,
        w1h, w1l, c1, d1, w2h, w2l, w3h, w3l, b3f, sqt, off);

    // single-launch exclusive scan: off -> global bucket start cursors
    scan_all<<<1, 1024, 0, stream>>>(off);

    // edge MLP (64 edges/wave): acquires slots via atomics on off, dual scatter
    edge_mlp_mfma<<<(ND / 64 + 3) / 4, 256, 0, stream>>>(
        x, sqt, pos, qidx, qattr, w1h, w1l, c1, d1,
        w2h, w2l, b2, w3h, w3l, b3f, off, msg);

    // node aggregation (off now holds bucket ends)
    node_out<<<4096, 256, 0, stream>>>(msg, off, out);
}

// Round 14
// 493.290 us; speedup vs baseline: 1.7135x; 1.7135x over previous
//
#include <hip/hip_runtime.h>
#include <math.h>

#define NN 100000
#define ND 1000000
#define INDIM 133
#define K1P 160                 // padded input dim (5 x 32)
#define NCNT (2*NN)
#define SCAN_CHUNK 2048
#define NBLK_SCAN ((NCNT + SCAN_CHUNK - 1) / SCAN_CHUNK)
#define HS 72                   // LDS h-tile row stride in bf16 elems (144B)
#define NBLK_X (NN / 4)         // 25000 stat blocks
#define NBLK_E ((ND + 255) / 256)

typedef __bf16 bf16x8 __attribute__((ext_vector_type(8)));
typedef __bf16 bf16x4 __attribute__((ext_vector_type(4)));
typedef float  f32x4  __attribute__((ext_vector_type(4)));
typedef _Float16 f16;
typedef _Float16 f16x4 __attribute__((ext_vector_type(4)));

__device__ __forceinline__ f32x4 mfma_bf16(bf16x8 a, bf16x8 b, f32x4 c) {
    return __builtin_amdgcn_mfma_f32_16x16x32_bf16(a, b, c, 0, 0, 0);
}

__device__ __forceinline__ float3 f3sub(float3 a, float3 b) {
    return make_float3(a.x - b.x, a.y - b.y, a.z - b.z);
}
__device__ __forceinline__ float3 f3cross(float3 a, float3 b) {
    return make_float3(a.y * b.z - a.z * b.y, a.z * b.x - a.x * b.z, a.x * b.y - a.y * b.x);
}
__device__ __forceinline__ float f3dot(float3 a, float3 b) {
    return a.x * b.x + a.y * b.y + a.z * b.z;
}
__device__ __forceinline__ float3 f3load(const float* __restrict__ p, int idx) {
    const float* q = p + (size_t)idx * 3;
    return make_float3(q[0], q[1], q[2]);
}
__device__ __forceinline__ float fsilu(float v) {
    return v / (1.0f + __expf(-v));
}

// ---- merged prep: weights (0..57) + per-node stats (58..58+24999) + count (rest) ----
__global__ __launch_bounds__(256) void prep_merged(
    const float* __restrict__ x,
    const float* __restrict__ w1, const float* __restrict__ b1,
    const float* __restrict__ w2,
    const float* __restrict__ w3, const float* __restrict__ b3,
    const float* __restrict__ wout,
    const float* __restrict__ gamma, const float* __restrict__ beta,
    const int* __restrict__ qidx,
    __bf16* __restrict__ w1h, __bf16* __restrict__ w1l,
    float* __restrict__ c1, float* __restrict__ d1,
    __bf16* __restrict__ w2h, __bf16* __restrict__ w2l,
    __bf16* __restrict__ w3h, __bf16* __restrict__ w3l,
    float* __restrict__ b3f,
    float2* __restrict__ sq,
    int* __restrict__ cnt)     // pre-zeroed; histogram of j (buckets 0..NN) and k (NN..2NN)
{
    const int b = blockIdx.x, tid = threadIdx.x;
    if (b < 40) {                       // w1g = diag(gamma) @ w1, [n][k] padded, hi/lo
        int idx = b * 256 + tid;        // 40*256 = 10240 = 64*160 exactly
        int n = idx / K1P, kp = idx - n * K1P;
        float v = (kp < INDIM) ? gamma[kp] * w1[(size_t)kp * 64 + n] : 0.0f;
        __bf16 h = (__bf16)v;
        w1h[idx] = h;
        w1l[idx] = (__bf16)(v - (float)h);
    } else if (b == 40) {               // c1 = gamma@w1, d1 = beta@w1 + b1
        if (tid < 64) {
            float sc = 0.0f, sd = 0.0f;
            for (int k = 0; k < INDIM; ++k) {
                float wv = w1[(size_t)k * 64 + tid];
                sc = fmaf(gamma[k], wv, sc);
                sd = fmaf(beta[k], wv, sd);
            }
            c1[tid] = sc;
            d1[tid] = sd + b1[tid];
        }
    } else if (b < 57) {                // w2 transposed [n][k'], permuted k
        int idx = (b - 41) * 256 + tid; // 16*256 = 4096
        int n = idx >> 6, kp = idx & 63;
        int ko = 16 * (kp & 3) + (kp >> 2);
        float v = w2[(size_t)ko * 64 + n];
        __bf16 h = (__bf16)v;
        w2h[idx] = h;
        w2l[idx] = (__bf16)(v - (float)h);
    } else if (b == 57) {               // w3'' = (w3 @ wout) * 2^-4, [c][k'] permuted
        for (int idx = tid; idx < 64 * 64; idx += 256) {
            int k = idx >> 6, c = idx & 63;
            float s = 0.0f;
            for (int q = 0; q < 64; ++q)
                s = fmaf(w3[(size_t)k * 64 + q], wout[(size_t)q * 64 + c], s);
            s *= 0.0625f;
            __bf16 h = (__bf16)s;
            int kp = 4 * (k & 15) + (k >> 4);
            w3h[(size_t)c * 64 + kp] = h;
            w3l[(size_t)c * 64 + kp] = (__bf16)(s - (float)h);
        }
        if (tid < 64) {
            float s = 0.0f;
            for (int q = 0; q < 64; ++q)
                s = fmaf(b3[q], wout[(size_t)q * 64 + tid], s);
            b3f[tid] = s * 0.0625f;
        }
    } else if (b < 58 + NBLK_X) {       // per-node LN stats
        const int n = (b - 58) * 4 + (tid >> 6);
        const int c = tid & 63;
        float v = x[(size_t)n * 64 + c];
        float s = v, q = v * v;
#pragma unroll
        for (int d = 1; d < 64; d <<= 1) {
            s += __shfl_xor(s, d);
            q += __shfl_xor(q, d);
        }
        if (c == 0) sq[n] = make_float2(s, q);
    } else {                            // degree histogram (j then k)
        int e = (b - 58 - NBLK_X) * 256 + tid;
        if (e < ND) {
            atomicAdd(&cnt[qidx[ND + e]], 1);
            atomicAdd(&cnt[NN + qidx[2 * ND + e]], 1);
        }
    }
}

// ---- counting-sort scans (R8/R12-proven 3-dispatch form) ----
__global__ __launch_bounds__(256) void scan1(int* data, int* __restrict__ bsum) {
    __shared__ int lds[256];
    const int tid = threadIdx.x;
    const int base = blockIdx.x * SCAN_CHUNK + tid * 8;
    int v[8];
    int tsum = 0;
#pragma unroll
    for (int t = 0; t < 8; ++t) {
        v[t] = (base + t < NCNT) ? data[base + t] : 0;
        tsum += v[t];
    }
    lds[tid] = tsum;
    __syncthreads();
    for (int d = 1; d < 256; d <<= 1) {
        int u = 0;
        if (tid >= d) u = lds[tid - d];
        __syncthreads();
        lds[tid] += u;
        __syncthreads();
    }
    if (tid == 255) bsum[blockIdx.x] = lds[255];
    int run = lds[tid] - tsum;
#pragma unroll
    for (int t = 0; t < 8; ++t) {
        if (base + t < NCNT) data[base + t] = run;
        run += v[t];
    }
}

__global__ __launch_bounds__(128) void scan2(int* __restrict__ bsum) {
    __shared__ int lds[128];
    const int t = threadIdx.x;
    int v = (t < NBLK_SCAN) ? bsum[t] : 0;
    lds[t] = v;
    __syncthreads();
    for (int d = 1; d < 128; d <<= 1) {
        int u = (t >= d) ? lds[t - d] : 0;
        __syncthreads();
        lds[t] += u;
        __syncthreads();
    }
    if (t < NBLK_SCAN) bsum[t] = lds[t] - v;
}

__global__ __launch_bounds__(256) void scan3(int* __restrict__ off,
                                             const int* __restrict__ bsum) {
    const int base = blockIdx.x * SCAN_CHUNK + threadIdx.x * 8;
    const int add = bsum[blockIdx.x];
#pragma unroll
    for (int t = 0; t < 8; ++t) {
        int i = base + t;
        if (i < NCNT) off[i] += add;
    }
}

// ---- edge MLP: R12 body + s_setprio around the pure-MFMA clusters (T5) ----
__global__ __launch_bounds__(256, 3) void edge_mlp_mfma(
    const float* __restrict__ x,
    const float2* __restrict__ sq,
    const float* __restrict__ pos,
    const int* __restrict__ qidx, const float* __restrict__ qattr,
    const __bf16* __restrict__ w1h, const __bf16* __restrict__ w1l,
    const float* __restrict__ c1, const float* __restrict__ d1,
    const __bf16* __restrict__ w2h, const __bf16* __restrict__ w2l, const float* __restrict__ b2,
    const __bf16* __restrict__ w3h, const __bf16* __restrict__ w3l, const float* __restrict__ b3f,
    int* __restrict__ off,        // global bucket cursors (post-scan); mutated to bucket ends
    f16* __restrict__ msg)
{
    __shared__ __align__(16) __bf16 hsh[4][4][16 * HS];   // 36 KB

    const int tid = threadIdx.x;
    const int w   = tid >> 6;
    const int l   = tid & 63;
    const int m   = l & 15;
    const int kg  = l >> 4;
    const int ebase = (blockIdx.x * 4 + w) * 64;
    if (ebase >= ND) return;               // no barriers: early-out safe

    // ---- slot acquisition: one edge per lane, issued first so the atomic
    // round-trip hides under the whole MFMA body ----
    int vj, vk;
    {
        const int me = ebase + l;
        vj = atomicAdd(&off[qidx[ND + me]], 1);
        vk = atomicAdd(&off[NN + qidx[2 * ND + me]], 1);
    }

    int iA[4], lA[4];
#pragma unroll
    for (int t = 0; t < 4; ++t) {
        const int e = ebase + 16 * t + m;
        iA[t] = qidx[e];
        lA[t] = qidx[3 * ND + e];
    }

    // ---- dihedral + raw-extras: lane handles tile kg, edge m (all 64 lanes busy) ----
    float cosd, sind, at0, at1, at2, se, qe;
    {
        const int e2 = ebase + 16 * kg + m;
        const int i2 = qidx[e2];
        const int j2 = qidx[ND + e2];
        const int k2 = qidx[2 * ND + e2];
        const int l2 = qidx[3 * ND + e2];
        float3 pi = f3load(pos, i2), pj = f3load(pos, j2);
        float3 pk = f3load(pos, k2), pl = f3load(pos, l2);
        float3 d1v_ = f3sub(pj, pi);
        float3 d2v_ = f3sub(pk, pj);
        float3 d3v_ = f3sub(pl, pk);
        float3 n1 = f3cross(d1v_, d2v_);
        float3 n2 = f3cross(d2v_, d3v_);
        float r1 = 1.0f / fmaxf(sqrtf(f3dot(n1, n1)), 1e-6f);
        n1.x *= r1; n1.y *= r1; n1.z *= r1;
        float r2 = 1.0f / fmaxf(sqrtf(f3dot(n2, n2)), 1e-6f);
        n2.x *= r2; n2.y *= r2; n2.z *= r2;
        cosd = fminf(fmaxf(f3dot(n1, n2), -1.0f), 1.0f);
        float rb = 1.0f / fmaxf(sqrtf(f3dot(d2v_, d2v_)), 1e-6f);
        float3 b2n = make_float3(d2v_.x * rb, d2v_.y * rb, d2v_.z * rb);
        float3 mm = f3cross(n1, b2n);
        sind = f3dot(mm, n2);
        at0 = qattr[(size_t)e2 * 3 + 0];
        at1 = qattr[(size_t)e2 * 3 + 1];
        at2 = qattr[(size_t)e2 * 3 + 2];
        se = at0 + at1 + at2 + cosd + sind;
        qe = at0 * at0 + at1 * at1 + at2 * at2 + cosd * cosd + sind * sind;
    }

    bf16x8 ah4[4], al4[4];
    float rs_[4], mn_[4];
#pragma unroll
    for (int t = 0; t < 4; ++t) {
        const int src = m + 16 * t;
        float u4[8] = {__shfl(at0, src), __shfl(at1, src), __shfl(at2, src),
                       __shfl(cosd, src), __shfl(sind, src), 0.f, 0.f, 0.f};
        float g0 = (kg == 0) ? 1.0f : 0.0f;
#pragma unroll
        for (int j = 0; j < 8; ++j) {
            float v = u4[j] * g0;
            __bf16 h = (__bf16)v;
            ah4[t][j] = h;
            al4[t][j] = (__bf16)(v - (float)h);
        }
        float2 si = sq[iA[t]], sl = sq[lA[t]];
        float S = si.x + sl.x + __shfl(se, src);
        float Q = si.y + sl.y + __shfl(qe, src);
        float mu  = S * (1.0f / INDIM);
        float var = Q * (1.0f / INDIM) - mu * mu;
        float rsv = rsqrtf(fmaxf(var, 0.0f) + 1e-5f);
        rs_[t] = rsv;
        mn_[t] = -mu * rsv;
    }

    // ---- layer 1: P = raw_x @ w1g (+ extras), split 3-MFMA ----
    f32x4 acc[4][4];
#pragma unroll
    for (int t = 0; t < 4; ++t)
#pragma unroll
        for (int nt = 0; nt < 4; ++nt) acc[t][nt] = (f32x4){0.f, 0.f, 0.f, 0.f};

    __builtin_amdgcn_s_setprio(1);
#pragma unroll
    for (int nt = 0; nt < 4; ++nt) {
        const size_t wb = (size_t)(16 * nt + m) * K1P + 128 + 8 * kg;
        bf16x8 bh = *(const bf16x8*)(w1h + wb);
        bf16x8 bl = *(const bf16x8*)(w1l + wb);
#pragma unroll
        for (int t = 0; t < 4; ++t) {
            acc[t][nt] = mfma_bf16(ah4[t], bh, acc[t][nt]);
            acc[t][nt] = mfma_bf16(al4[t], bh, acc[t][nt]);
            acc[t][nt] = mfma_bf16(ah4[t], bl, acc[t][nt]);
        }
    }
    __builtin_amdgcn_s_setprio(0);

#pragma unroll
    for (int s = 0; s < 4; ++s) {
        const int colo = 32 * (s & 1) + 8 * kg;
        bf16x8 ath[4], atl[4];
#pragma unroll
        for (int t = 0; t < 4; ++t) {
            const int r_ = (s < 2) ? iA[t] : lA[t];
            float vv[8];
            *(float4*)&vv[0] = *(const float4*)(x + (size_t)r_ * 64 + colo);
            *(float4*)&vv[4] = *(const float4*)(x + (size_t)r_ * 64 + colo + 4);
#pragma unroll
            for (int j = 0; j < 8; ++j) {
                float v = vv[j];
                __bf16 h = (__bf16)v;
                ath[t][j] = h;
                atl[t][j] = (__bf16)(v - (float)h);
            }
        }
        __builtin_amdgcn_s_setprio(1);
#pragma unroll
        for (int nt = 0; nt < 4; ++nt) {
            const size_t wb = (size_t)(16 * nt + m) * K1P + 32 * s + 8 * kg;
            bf16x8 bh = *(const bf16x8*)(w1h + wb);
            bf16x8 bl = *(const bf16x8*)(w1l + wb);
#pragma unroll
            for (int t = 0; t < 4; ++t) {
                acc[t][nt] = mfma_bf16(ath[t], bh, acc[t][nt]);
                acc[t][nt] = mfma_bf16(atl[t], bh, acc[t][nt]);
                acc[t][nt] = mfma_bf16(ath[t], bl, acc[t][nt]);
            }
        }
        __builtin_amdgcn_s_setprio(0);
    }

    // epilogue 1: h1 = silu(rs*P + (-rs*mu)*c1 + d1), permuted-col 8B LDS stores
    float c1v[4], d1v[4], b2v[4], b3v[4];
#pragma unroll
    for (int nt = 0; nt < 4; ++nt) {
        c1v[nt] = c1[16 * nt + m];
        d1v[nt] = d1[16 * nt + m];
        b2v[nt] = b2[16 * nt + m];
        b3v[nt] = b3f[16 * nt + m];
    }
#pragma unroll
    for (int t = 0; t < 4; ++t) {
        __bf16* hhw = &hsh[w][t][0];
#pragma unroll
        for (int r = 0; r < 4; ++r) {
            float rse = __shfl(rs_[t], 4 * kg + r);
            float mne = __shfl(mn_[t], 4 * kg + r);
            bf16x4 hv4;
#pragma unroll
            for (int nt = 0; nt < 4; ++nt)
                hv4[nt] = (__bf16)fsilu(fmaf(rse, acc[t][nt][r],
                                        fmaf(mne, c1v[nt], d1v[nt])));
            *(bf16x4*)(hhw + (4 * kg + r) * HS + m * 4) = hv4;
        }
    }

    // ---- layer 2: hi-A x split-W ----
    bf16x8 a2h[4][2];
#pragma unroll
    for (int t = 0; t < 4; ++t)
#pragma unroll
        for (int s = 0; s < 2; ++s)
            a2h[t][s] = *(const bf16x8*)(&hsh[w][t][m * HS + 32 * s + 8 * kg]);
    f32x4 acc2[4][4];
#pragma unroll
    for (int t = 0; t < 4; ++t)
#pragma unroll
        for (int nt = 0; nt < 4; ++nt) acc2[t][nt] = (f32x4){0.f, 0.f, 0.f, 0.f};
    __builtin_amdgcn_s_setprio(1);
#pragma unroll
    for (int s = 0; s < 2; ++s) {
#pragma unroll
        for (int nt = 0; nt < 4; ++nt) {
            const size_t wb = (size_t)(16 * nt + m) * 64 + 32 * s + 8 * kg;
            bf16x8 bh = *(const bf16x8*)(w2h + wb);
            bf16x8 bl = *(const bf16x8*)(w2l + wb);
#pragma unroll
            for (int t = 0; t < 4; ++t) {
                acc2[t][nt] = mfma_bf16(a2h[t][s], bh, acc2[t][nt]);
                acc2[t][nt] = mfma_bf16(a2h[t][s], bl, acc2[t][nt]);
            }
        }
    }
    __builtin_amdgcn_s_setprio(0);
#pragma unroll
    for (int t = 0; t < 4; ++t) {
        __bf16* hhw = &hsh[w][t][0];
#pragma unroll
        for (int r = 0; r < 4; ++r) {
            bf16x4 hv4;
#pragma unroll
            for (int nt = 0; nt < 4; ++nt)
                hv4[nt] = (__bf16)fsilu(acc2[t][nt][r] + b2v[nt]);
            *(bf16x4*)(hhw + (4 * kg + r) * HS + m * 4) = hv4;
        }
    }

    // ---- layer 3 (w_out + scale folded) ----
    bf16x8 a3h[4][2];
#pragma unroll
    for (int t = 0; t < 4; ++t)
#pragma unroll
        for (int s = 0; s < 2; ++s)
            a3h[t][s] = *(const bf16x8*)(&hsh[w][t][m * HS + 32 * s + 8 * kg]);
    f32x4 acc3[4][4];
#pragma unroll
    for (int t = 0; t < 4; ++t)
#pragma unroll
        for (int nt = 0; nt < 4; ++nt) acc3[t][nt] = (f32x4){0.f, 0.f, 0.f, 0.f};
    __builtin_amdgcn_s_setprio(1);
#pragma unroll
    for (int s = 0; s < 2; ++s) {
#pragma unroll
        for (int nt = 0; nt < 4; ++nt) {
            const size_t wb = (size_t)(16 * nt + m) * 64 + 32 * s + 8 * kg;
            bf16x8 bh = *(const bf16x8*)(w3h + wb);
            bf16x8 bl = *(const bf16x8*)(w3l + wb);
#pragma unroll
            for (int t = 0; t < 4; ++t) {
                acc3[t][nt] = mfma_bf16(a3h[t][s], bh, acc3[t][nt]);
                acc3[t][nt] = mfma_bf16(a3h[t][s], bl, acc3[t][nt]);
            }
        }
    }
    __builtin_amdgcn_s_setprio(0);

    // ---- msg: f16x4 stores to BOTH sorted slots; slot of edge er lives in
    // lane er-ebase = 16t+4kg+r (per-lane shfl src) ----
#pragma unroll
    for (int t = 0; t < 4; ++t) {
#pragma unroll
        for (int r = 0; r < 4; ++r) {
            f16x4 v;
#pragma unroll
            for (int nt = 0; nt < 4; ++nt)
                v[nt] = (f16)(acc3[t][nt][r] + b3v[nt]);
            const int src = 16 * t + 4 * kg + r;
            const int sjv = __shfl(vj, src);
            const int skv = __shfl(vk, src);
            *(f16x4*)(msg + (size_t)sjv * 64 + m * 4) = v;
            *(f16x4*)(msg + (size_t)skv * 64 + m * 4) = v;
        }
    }
}

// ---- node aggregation: R8-proven whole-wave form (uniform bounds, shfl reduce) ----
__global__ __launch_bounds__(256) void node_out(const f16* __restrict__ msg,
                                                const int* __restrict__ off,
                                                float* __restrict__ out) {
    const int w   = threadIdx.x >> 6;
    const int l   = threadIdx.x & 63;
    const int sub = l >> 4;      // row-within-4-chunk
    const int m16 = l & 15;      // permuted col group: cols' 4*m16..+3
    for (int n = blockIdx.x * 4 + w; n < NN; n += gridDim.x * 4) {
        int ja = (n == 0) ? 0 : off[n - 1];
        int jb = off[n];
        int ka = off[NN + n - 1];   // n==0 -> off[NN-1] = start of k-region
        int kb = off[NN + n];
        float s0 = 0.f, s1 = 0.f, s2 = 0.f, s3 = 0.f;
        float t0 = 0.f, t1 = 0.f, t2 = 0.f, t3 = 0.f;
        for (int p = ja + sub; p < jb; p += 4) {
            f16x4 v = *(const f16x4*)(msg + (size_t)p * 64 + m16 * 4);
            s0 += (float)v[0]; s1 += (float)v[1];
            s2 += (float)v[2]; s3 += (float)v[3];
        }
        for (int p = ka + sub; p < kb; p += 4) {
            f16x4 v = *(const f16x4*)(msg + (size_t)p * 64 + m16 * 4);
            t0 += (float)v[0]; t1 += (float)v[1];
            t2 += (float)v[2]; t3 += (float)v[3];
        }
        s0 += __shfl_xor(s0, 16); s0 += __shfl_xor(s0, 32);
        s1 += __shfl_xor(s1, 16); s1 += __shfl_xor(s1, 32);
        s2 += __shfl_xor(s2, 16); s2 += __shfl_xor(s2, 32);
        s3 += __shfl_xor(s3, 16); s3 += __shfl_xor(s3, 32);
        t0 += __shfl_xor(t0, 16); t0 += __shfl_xor(t0, 32);
        t1 += __shfl_xor(t1, 16); t1 += __shfl_xor(t1, 32);
        t2 += __shfl_xor(t2, 16); t2 += __shfl_xor(t2, 32);
        t3 += __shfl_xor(t3, 16); t3 += __shfl_xor(t3, 32);
        if (sub == 0) {
            float rj = 1.0f / fmaxf((float)(jb - ja), 1.0f);
            float rk = 1.0f / fmaxf((float)(kb - ka), 1.0f);
            float* o = out + (size_t)n * 64;
            o[m16]      = s0 * rj + t0 * rk;   // col' 4m+nt <-> true col 16nt+m
            o[16 + m16] = s1 * rj + t1 * rk;
            o[32 + m16] = s2 * rj + t2 * rk;
            o[48 + m16] = s3 * rj + t3 * rk;
        }
    }
}

// ============================ launch ============================

extern "C" void kernel_launch(void* const* d_in, const int* in_sizes, int n_in,
                              void* d_out, int out_size, void* d_ws, size_t ws_size,
                              hipStream_t stream) {
    (void)in_sizes; (void)n_in; (void)out_size;

    const float* x     = (const float*)d_in[0];
    const float* pos   = (const float*)d_in[1];
    const int*   qidx  = (const int*)d_in[2];
    const float* qattr = (const float*)d_in[3];
    const float* gamma = (const float*)d_in[4];
    const float* beta  = (const float*)d_in[5];
    const float* w1    = (const float*)d_in[6];
    const float* b1    = (const float*)d_in[7];
    const float* w2    = (const float*)d_in[8];
    const float* b2    = (const float*)d_in[9];
    const float* w3    = (const float*)d_in[10];
    const float* b3    = (const float*)d_in[11];
    const float* w_out = (const float*)d_in[12];
    float* out = (float*)d_out;

    size_t o = 0;
    auto alloc = [&](size_t bytes) { size_t r = o; o = (o + bytes + 255) & ~(size_t)255; return r; };
    char* W = (char*)d_ws;
    f16*    msg    = (f16*)   (W + alloc((size_t)2 * ND * 64 * sizeof(f16)));   // 244 MiB
    int*    off    = (int*)   (W + alloc((size_t)NCNT * sizeof(int)));
    int*    bsum   = (int*)   (W + alloc((size_t)NBLK_SCAN * sizeof(int)));
    float2* sqt    = (float2*)(W + alloc((size_t)NN * sizeof(float2)));
    __bf16* w1h    = (__bf16*)(W + alloc((size_t)64 * K1P * sizeof(__bf16)));
    __bf16* w1l    = (__bf16*)(W + alloc((size_t)64 * K1P * sizeof(__bf16)));
    __bf16* w2h    = (__bf16*)(W + alloc((size_t)64 * 64 * sizeof(__bf16)));
    __bf16* w2l    = (__bf16*)(W + alloc((size_t)64 * 64 * sizeof(__bf16)));
    __bf16* w3h    = (__bf16*)(W + alloc((size_t)64 * 64 * sizeof(__bf16)));
    __bf16* w3l    = (__bf16*)(W + alloc((size_t)64 * 64 * sizeof(__bf16)));
    float*  c1     = (float*) (W + alloc((size_t)64 * sizeof(float)));
    float*  d1     = (float*) (W + alloc((size_t)64 * sizeof(float)));
    float*  b3f    = (float*) (W + alloc((size_t)64 * sizeof(float)));
    if (ws_size < o) return;   // ~245 MiB — well within proven ws bound

    // zero histogram, then merged prep (weights + stats + count in ONE launch)
    hipMemsetAsync(off, 0, (size_t)NCNT * sizeof(int), stream);
    prep_merged<<<58 + NBLK_X + NBLK_E, 256, 0, stream>>>(
        x, w1, b1, w2, w3, b3, w_out, gamma, beta, qidx,
        w1h, w1l, c1, d1, w2h, w2l, w3h, w3l, b3f, sqt, off);

    // 3-dispatch scan (R12-proven): off -> global bucket start cursors
    scan1<<<NBLK_SCAN, 256, 0, stream>>>(off, bsum);
    scan2<<<1, 128, 0, stream>>>(bsum);
    scan3<<<NBLK_SCAN, 256, 0, stream>>>(off, bsum);

    // edge MLP (64 edges/wave): acquires slots via atomics on off, dual scatter
    edge_mlp_mfma<<<(ND / 64 + 3) / 4, 256, 0, stream>>>(
        x, sqt, pos, qidx, qattr, w1h, w1l, c1, d1,
        w2h, w2l, b2, w3h, w3l, b3f, off, msg);

    // node aggregation (off now holds bucket ends)
    node_out<<<4096, 256, 0, stream>>>(msg, off, out);
}

// Round 15
// 484.573 us; speedup vs baseline: 1.7444x; 1.0180x over previous
//
#include <hip/hip_runtime.h>
#include <math.h>

#define NN 100000
#define ND 1000000
#define INDIM 133
#define K1P 160                 // padded input dim (5 x 32)
#define NCNT (2*NN)
#define SCAN_CHUNK 2048
#define NBLK_SCAN ((NCNT + SCAN_CHUNK - 1) / SCAN_CHUNK)
#define HS 72                   // LDS h-tile row stride in bf16 elems (144B)
#define NBLK_X (NN / 4)         // 25000 stat blocks
#define NBLK_E ((ND + 255) / 256)

typedef __bf16 bf16x8 __attribute__((ext_vector_type(8)));
typedef __bf16 bf16x4 __attribute__((ext_vector_type(4)));
typedef float  f32x4  __attribute__((ext_vector_type(4)));
typedef _Float16 f16;
typedef _Float16 f16x4 __attribute__((ext_vector_type(4)));

__device__ __forceinline__ f32x4 mfma_bf16(bf16x8 a, bf16x8 b, f32x4 c) {
    return __builtin_amdgcn_mfma_f32_16x16x32_bf16(a, b, c, 0, 0, 0);
}

__device__ __forceinline__ float3 f3sub(float3 a, float3 b) {
    return make_float3(a.x - b.x, a.y - b.y, a.z - b.z);
}
__device__ __forceinline__ float3 f3cross(float3 a, float3 b) {
    return make_float3(a.y * b.z - a.z * b.y, a.z * b.x - a.x * b.z, a.x * b.y - a.y * b.x);
}
__device__ __forceinline__ float f3dot(float3 a, float3 b) {
    return a.x * b.x + a.y * b.y + a.z * b.z;
}
__device__ __forceinline__ float3 f3load(const float* __restrict__ p, int idx) {
    const float* q = p + (size_t)idx * 3;
    return make_float3(q[0], q[1], q[2]);
}
__device__ __forceinline__ float fsilu(float v) {
    return v / (1.0f + __expf(-v));
}

// ---- merged prep: weights (0..57) + per-node stats (58..58+24999) + count (rest) ----
__global__ __launch_bounds__(256) void prep_merged(
    const float* __restrict__ x,
    const float* __restrict__ w1, const float* __restrict__ b1,
    const float* __restrict__ w2,
    const float* __restrict__ w3, const float* __restrict__ b3,
    const float* __restrict__ wout,
    const float* __restrict__ gamma, const float* __restrict__ beta,
    const int* __restrict__ qidx,
    __bf16* __restrict__ w1h, __bf16* __restrict__ w1l,
    float* __restrict__ c1, float* __restrict__ d1,
    __bf16* __restrict__ w2h, __bf16* __restrict__ w2l,
    __bf16* __restrict__ w3h, __bf16* __restrict__ w3l,
    float* __restrict__ b3f,
    float2* __restrict__ sq,
    int* __restrict__ cnt)     // pre-zeroed; histogram of j (buckets 0..NN) and k (NN..2NN)
{
    const int b = blockIdx.x, tid = threadIdx.x;
    if (b < 40) {                       // w1g = diag(gamma) @ w1, [n][k] padded, hi/lo
        int idx = b * 256 + tid;        // 40*256 = 10240 = 64*160 exactly
        int n = idx / K1P, kp = idx - n * K1P;
        float v = (kp < INDIM) ? gamma[kp] * w1[(size_t)kp * 64 + n] : 0.0f;
        __bf16 h = (__bf16)v;
        w1h[idx] = h;
        w1l[idx] = (__bf16)(v - (float)h);
    } else if (b == 40) {               // c1 = gamma@w1, d1 = beta@w1 + b1
        if (tid < 64) {
            float sc = 0.0f, sd = 0.0f;
            for (int k = 0; k < INDIM; ++k) {
                float wv = w1[(size_t)k * 64 + tid];
                sc = fmaf(gamma[k], wv, sc);
                sd = fmaf(beta[k], wv, sd);
            }
            c1[tid] = sc;
            d1[tid] = sd + b1[tid];
        }
    } else if (b < 57) {                // w2 transposed [n][k'], permuted k
        int idx = (b - 41) * 256 + tid; // 16*256 = 4096
        int n = idx >> 6, kp = idx & 63;
        int ko = 16 * (kp & 3) + (kp >> 2);
        float v = w2[(size_t)ko * 64 + n];
        __bf16 h = (__bf16)v;
        w2h[idx] = h;
        w2l[idx] = (__bf16)(v - (float)h);
    } else if (b == 57) {               // w3'' = (w3 @ wout) * 2^-4, [c][k'] permuted
        for (int idx = tid; idx < 64 * 64; idx += 256) {
            int k = idx >> 6, c = idx & 63;
            float s = 0.0f;
            for (int q = 0; q < 64; ++q)
                s = fmaf(w3[(size_t)k * 64 + q], wout[(size_t)q * 64 + c], s);
            s *= 0.0625f;
            __bf16 h = (__bf16)s;
            int kp = 4 * (k & 15) + (k >> 4);
            w3h[(size_t)c * 64 + kp] = h;
            w3l[(size_t)c * 64 + kp] = (__bf16)(s - (float)h);
        }
        if (tid < 64) {
            float s = 0.0f;
            for (int q = 0; q < 64; ++q)
                s = fmaf(b3[q], wout[(size_t)q * 64 + tid], s);
            b3f[tid] = s * 0.0625f;
        }
    } else if (b < 58 + NBLK_X) {       // per-node LN stats
        const int n = (b - 58) * 4 + (tid >> 6);
        const int c = tid & 63;
        float v = x[(size_t)n * 64 + c];
        float s = v, q = v * v;
#pragma unroll
        for (int d = 1; d < 64; d <<= 1) {
            s += __shfl_xor(s, d);
            q += __shfl_xor(q, d);
        }
        if (c == 0) sq[n] = make_float2(s, q);
    } else {                            // degree histogram (j then k)
        int e = (b - 58 - NBLK_X) * 256 + tid;
        if (e < ND) {
            atomicAdd(&cnt[qidx[ND + e]], 1);
            atomicAdd(&cnt[NN + qidx[2 * ND + e]], 1);
        }
    }
}

// ---- counting-sort scans (R8/R12-proven 3-dispatch form) ----
__global__ __launch_bounds__(256) void scan1(int* data, int* __restrict__ bsum) {
    __shared__ int lds[256];
    const int tid = threadIdx.x;
    const int base = blockIdx.x * SCAN_CHUNK + tid * 8;
    int v[8];
    int tsum = 0;
#pragma unroll
    for (int t = 0; t < 8; ++t) {
        v[t] = (base + t < NCNT) ? data[base + t] : 0;
        tsum += v[t];
    }
    lds[tid] = tsum;
    __syncthreads();
    for (int d = 1; d < 256; d <<= 1) {
        int u = 0;
        if (tid >= d) u = lds[tid - d];
        __syncthreads();
        lds[tid] += u;
        __syncthreads();
    }
    if (tid == 255) bsum[blockIdx.x] = lds[255];
    int run = lds[tid] - tsum;
#pragma unroll
    for (int t = 0; t < 8; ++t) {
        if (base + t < NCNT) data[base + t] = run;
        run += v[t];
    }
}

__global__ __launch_bounds__(128) void scan2(int* __restrict__ bsum) {
    __shared__ int lds[128];
    const int t = threadIdx.x;
    int v = (t < NBLK_SCAN) ? bsum[t] : 0;
    lds[t] = v;
    __syncthreads();
    for (int d = 1; d < 128; d <<= 1) {
        int u = (t >= d) ? lds[t - d] : 0;
        __syncthreads();
        lds[t] += u;
        __syncthreads();
    }
    if (t < NBLK_SCAN) bsum[t] = lds[t] - v;
}

__global__ __launch_bounds__(256) void scan3(int* __restrict__ off,
                                             const int* __restrict__ bsum) {
    const int base = blockIdx.x * SCAN_CHUNK + threadIdx.x * 8;
    const int add = bsum[blockIdx.x];
#pragma unroll
    for (int t = 0; t < 8; ++t) {
        int i = base + t;
        if (i < NCNT) off[i] += add;
    }
}

// ---- edge MLP: R12-proven body (64 edges/wave, 4 M-tiles per B-load, 36KB LDS,
// in-kernel slot acquisition; NO setprio — measured null in R14) ----
__global__ __launch_bounds__(256, 3) void edge_mlp_mfma(
    const float* __restrict__ x,
    const float2* __restrict__ sq,
    const float* __restrict__ pos,
    const int* __restrict__ qidx, const float* __restrict__ qattr,
    const __bf16* __restrict__ w1h, const __bf16* __restrict__ w1l,
    const float* __restrict__ c1, const float* __restrict__ d1,
    const __bf16* __restrict__ w2h, const __bf16* __restrict__ w2l, const float* __restrict__ b2,
    const __bf16* __restrict__ w3h, const __bf16* __restrict__ w3l, const float* __restrict__ b3f,
    int* __restrict__ off,        // global bucket cursors (post-scan); mutated to bucket ends
    f16* __restrict__ msg)
{
    __shared__ __align__(16) __bf16 hsh[4][4][16 * HS];   // 36 KB

    const int tid = threadIdx.x;
    const int w   = tid >> 6;
    const int l   = tid & 63;
    const int m   = l & 15;
    const int kg  = l >> 4;
    const int ebase = (blockIdx.x * 4 + w) * 64;
    if (ebase >= ND) return;               // no barriers: early-out safe

    // ---- slot acquisition: one edge per lane, issued first so the atomic
    // round-trip hides under the whole MFMA body ----
    int vj, vk;
    {
        const int me = ebase + l;
        vj = atomicAdd(&off[qidx[ND + me]], 1);
        vk = atomicAdd(&off[NN + qidx[2 * ND + me]], 1);
    }

    int iA[4], lA[4];
#pragma unroll
    for (int t = 0; t < 4; ++t) {
        const int e = ebase + 16 * t + m;
        iA[t] = qidx[e];
        lA[t] = qidx[3 * ND + e];
    }

    // ---- dihedral + raw-extras: lane handles tile kg, edge m (all 64 lanes busy) ----
    float cosd, sind, at0, at1, at2, se, qe;
    {
        const int e2 = ebase + 16 * kg + m;
        const int i2 = qidx[e2];
        const int j2 = qidx[ND + e2];
        const int k2 = qidx[2 * ND + e2];
        const int l2 = qidx[3 * ND + e2];
        float3 pi = f3load(pos, i2), pj = f3load(pos, j2);
        float3 pk = f3load(pos, k2), pl = f3load(pos, l2);
        float3 d1v_ = f3sub(pj, pi);
        float3 d2v_ = f3sub(pk, pj);
        float3 d3v_ = f3sub(pl, pk);
        float3 n1 = f3cross(d1v_, d2v_);
        float3 n2 = f3cross(d2v_, d3v_);
        float r1 = 1.0f / fmaxf(sqrtf(f3dot(n1, n1)), 1e-6f);
        n1.x *= r1; n1.y *= r1; n1.z *= r1;
        float r2 = 1.0f / fmaxf(sqrtf(f3dot(n2, n2)), 1e-6f);
        n2.x *= r2; n2.y *= r2; n2.z *= r2;
        cosd = fminf(fmaxf(f3dot(n1, n2), -1.0f), 1.0f);
        float rb = 1.0f / fmaxf(sqrtf(f3dot(d2v_, d2v_)), 1e-6f);
        float3 b2n = make_float3(d2v_.x * rb, d2v_.y * rb, d2v_.z * rb);
        float3 mm = f3cross(n1, b2n);
        sind = f3dot(mm, n2);
        at0 = qattr[(size_t)e2 * 3 + 0];
        at1 = qattr[(size_t)e2 * 3 + 1];
        at2 = qattr[(size_t)e2 * 3 + 2];
        se = at0 + at1 + at2 + cosd + sind;
        qe = at0 * at0 + at1 * at1 + at2 * at2 + cosd * cosd + sind * sind;
    }

    bf16x8 ah4[4], al4[4];
    float rs_[4], mn_[4];
#pragma unroll
    for (int t = 0; t < 4; ++t) {
        const int src = m + 16 * t;
        float u4[8] = {__shfl(at0, src), __shfl(at1, src), __shfl(at2, src),
                       __shfl(cosd, src), __shfl(sind, src), 0.f, 0.f, 0.f};
        float g0 = (kg == 0) ? 1.0f : 0.0f;
#pragma unroll
        for (int j = 0; j < 8; ++j) {
            float v = u4[j] * g0;
            __bf16 h = (__bf16)v;
            ah4[t][j] = h;
            al4[t][j] = (__bf16)(v - (float)h);
        }
        float2 si = sq[iA[t]], sl = sq[lA[t]];
        float S = si.x + sl.x + __shfl(se, src);
        float Q = si.y + sl.y + __shfl(qe, src);
        float mu  = S * (1.0f / INDIM);
        float var = Q * (1.0f / INDIM) - mu * mu;
        float rsv = rsqrtf(fmaxf(var, 0.0f) + 1e-5f);
        rs_[t] = rsv;
        mn_[t] = -mu * rsv;
    }

    // ---- layer 1: P = raw_x @ w1g (+ extras), split 3-MFMA ----
    f32x4 acc[4][4];
#pragma unroll
    for (int t = 0; t < 4; ++t)
#pragma unroll
        for (int nt = 0; nt < 4; ++nt) acc[t][nt] = (f32x4){0.f, 0.f, 0.f, 0.f};

#pragma unroll
    for (int nt = 0; nt < 4; ++nt) {
        const size_t wb = (size_t)(16 * nt + m) * K1P + 128 + 8 * kg;
        bf16x8 bh = *(const bf16x8*)(w1h + wb);
        bf16x8 bl = *(const bf16x8*)(w1l + wb);
#pragma unroll
        for (int t = 0; t < 4; ++t) {
            acc[t][nt] = mfma_bf16(ah4[t], bh, acc[t][nt]);
            acc[t][nt] = mfma_bf16(al4[t], bh, acc[t][nt]);
            acc[t][nt] = mfma_bf16(ah4[t], bl, acc[t][nt]);
        }
    }

#pragma unroll
    for (int s = 0; s < 4; ++s) {
        const int colo = 32 * (s & 1) + 8 * kg;
        bf16x8 ath[4], atl[4];
#pragma unroll
        for (int t = 0; t < 4; ++t) {
            const int r_ = (s < 2) ? iA[t] : lA[t];
            float vv[8];
            *(float4*)&vv[0] = *(const float4*)(x + (size_t)r_ * 64 + colo);
            *(float4*)&vv[4] = *(const float4*)(x + (size_t)r_ * 64 + colo + 4);
#pragma unroll
            for (int j = 0; j < 8; ++j) {
                float v = vv[j];
                __bf16 h = (__bf16)v;
                ath[t][j] = h;
                atl[t][j] = (__bf16)(v - (float)h);
            }
        }
#pragma unroll
        for (int nt = 0; nt < 4; ++nt) {
            const size_t wb = (size_t)(16 * nt + m) * K1P + 32 * s + 8 * kg;
            bf16x8 bh = *(const bf16x8*)(w1h + wb);
            bf16x8 bl = *(const bf16x8*)(w1l + wb);
#pragma unroll
            for (int t = 0; t < 4; ++t) {
                acc[t][nt] = mfma_bf16(ath[t], bh, acc[t][nt]);
                acc[t][nt] = mfma_bf16(atl[t], bh, acc[t][nt]);
                acc[t][nt] = mfma_bf16(ath[t], bl, acc[t][nt]);
            }
        }
    }

    // epilogue 1: h1 = silu(rs*P + (-rs*mu)*c1 + d1), permuted-col 8B LDS stores
    float c1v[4], d1v[4], b2v[4], b3v[4];
#pragma unroll
    for (int nt = 0; nt < 4; ++nt) {
        c1v[nt] = c1[16 * nt + m];
        d1v[nt] = d1[16 * nt + m];
        b2v[nt] = b2[16 * nt + m];
        b3v[nt] = b3f[16 * nt + m];
    }
#pragma unroll
    for (int t = 0; t < 4; ++t) {
        __bf16* hhw = &hsh[w][t][0];
#pragma unroll
        for (int r = 0; r < 4; ++r) {
            float rse = __shfl(rs_[t], 4 * kg + r);
            float mne = __shfl(mn_[t], 4 * kg + r);
            bf16x4 hv4;
#pragma unroll
            for (int nt = 0; nt < 4; ++nt)
                hv4[nt] = (__bf16)fsilu(fmaf(rse, acc[t][nt][r],
                                        fmaf(mne, c1v[nt], d1v[nt])));
            *(bf16x4*)(hhw + (4 * kg + r) * HS + m * 4) = hv4;
        }
    }

    // ---- layer 2: hi-A x split-W ----
    bf16x8 a2h[4][2];
#pragma unroll
    for (int t = 0; t < 4; ++t)
#pragma unroll
        for (int s = 0; s < 2; ++s)
            a2h[t][s] = *(const bf16x8*)(&hsh[w][t][m * HS + 32 * s + 8 * kg]);
    f32x4 acc2[4][4];
#pragma unroll
    for (int t = 0; t < 4; ++t)
#pragma unroll
        for (int nt = 0; nt < 4; ++nt) acc2[t][nt] = (f32x4){0.f, 0.f, 0.f, 0.f};
#pragma unroll
    for (int s = 0; s < 2; ++s) {
#pragma unroll
        for (int nt = 0; nt < 4; ++nt) {
            const size_t wb = (size_t)(16 * nt + m) * 64 + 32 * s + 8 * kg;
            bf16x8 bh = *(const bf16x8*)(w2h + wb);
            bf16x8 bl = *(const bf16x8*)(w2l + wb);
#pragma unroll
            for (int t = 0; t < 4; ++t) {
                acc2[t][nt] = mfma_bf16(a2h[t][s], bh, acc2[t][nt]);
                acc2[t][nt] = mfma_bf16(a2h[t][s], bl, acc2[t][nt]);
            }
        }
    }
#pragma unroll
    for (int t = 0; t < 4; ++t) {
        __bf16* hhw = &hsh[w][t][0];
#pragma unroll
        for (int r = 0; r < 4; ++r) {
            bf16x4 hv4;
#pragma unroll
            for (int nt = 0; nt < 4; ++nt)
                hv4[nt] = (__bf16)fsilu(acc2[t][nt][r] + b2v[nt]);
            *(bf16x4*)(hhw + (4 * kg + r) * HS + m * 4) = hv4;
        }
    }

    // ---- layer 3 (w_out + scale folded) ----
    bf16x8 a3h[4][2];
#pragma unroll
    for (int t = 0; t < 4; ++t)
#pragma unroll
        for (int s = 0; s < 2; ++s)
            a3h[t][s] = *(const bf16x8*)(&hsh[w][t][m * HS + 32 * s + 8 * kg]);
    f32x4 acc3[4][4];
#pragma unroll
    for (int t = 0; t < 4; ++t)
#pragma unroll
        for (int nt = 0; nt < 4; ++nt) acc3[t][nt] = (f32x4){0.f, 0.f, 0.f, 0.f};
#pragma unroll
    for (int s = 0; s < 2; ++s) {
#pragma unroll
        for (int nt = 0; nt < 4; ++nt) {
            const size_t wb = (size_t)(16 * nt + m) * 64 + 32 * s + 8 * kg;
            bf16x8 bh = *(const bf16x8*)(w3h + wb);
            bf16x8 bl = *(const bf16x8*)(w3l + wb);
#pragma unroll
            for (int t = 0; t < 4; ++t) {
                acc3[t][nt] = mfma_bf16(a3h[t][s], bh, acc3[t][nt]);
                acc3[t][nt] = mfma_bf16(a3h[t][s], bl, acc3[t][nt]);
            }
        }
    }

    // ---- msg: f16x4 stores to BOTH sorted slots; slot of edge er lives in
    // lane er-ebase = 16t+4kg+r (per-lane shfl src) ----
#pragma unroll
    for (int t = 0; t < 4; ++t) {
#pragma unroll
        for (int r = 0; r < 4; ++r) {
            f16x4 v;
#pragma unroll
            for (int nt = 0; nt < 4; ++nt)
                v[nt] = (f16)(acc3[t][nt][r] + b3v[nt]);
            const int src = 16 * t + 4 * kg + r;
            const int sjv = __shfl(vj, src);
            const int skv = __shfl(vk, src);
            *(f16x4*)(msg + (size_t)sjv * 64 + m * 4) = v;
            *(f16x4*)(msg + (size_t)skv * 64 + m * 4) = v;
        }
    }
}

// ---- node aggregation: R8-proven whole-wave form (uniform bounds, shfl reduce) ----
__global__ __launch_bounds__(256) void node_out(const f16* __restrict__ msg,
                                                const int* __restrict__ off,
                                                float* __restrict__ out) {
    const int w   = threadIdx.x >> 6;
    const int l   = threadIdx.x & 63;
    const int sub = l >> 4;      // row-within-4-chunk
    const int m16 = l & 15;      // permuted col group: cols' 4*m16..+3
    for (int n = blockIdx.x * 4 + w; n < NN; n += gridDim.x * 4) {
        int ja = (n == 0) ? 0 : off[n - 1];
        int jb = off[n];
        int ka = off[NN + n - 1];   // n==0 -> off[NN-1] = start of k-region
        int kb = off[NN + n];
        float s0 = 0.f, s1 = 0.f, s2 = 0.f, s3 = 0.f;
        float t0 = 0.f, t1 = 0.f, t2 = 0.f, t3 = 0.f;
        for (int p = ja + sub; p < jb; p += 4) {
            f16x4 v = *(const f16x4*)(msg + (size_t)p * 64 + m16 * 4);
            s0 += (float)v[0]; s1 += (float)v[1];
            s2 += (float)v[2]; s3 += (float)v[3];
        }
        for (int p = ka + sub; p < kb; p += 4) {
            f16x4 v = *(const f16x4*)(msg + (size_t)p * 64 + m16 * 4);
            t0 += (float)v[0]; t1 += (float)v[1];
            t2 += (float)v[2]; t3 += (float)v[3];
        }
        s0 += __shfl_xor(s0, 16); s0 += __shfl_xor(s0, 32);
        s1 += __shfl_xor(s1, 16); s1 += __shfl_xor(s1, 32);
        s2 += __shfl_xor(s2, 16); s2 += __shfl_xor(s2, 32);
        s3 += __shfl_xor(s3, 16); s3 += __shfl_xor(s3, 32);
        t0 += __shfl_xor(t0, 16); t0 += __shfl_xor(t0, 32);
        t1 += __shfl_xor(t1, 16); t1 += __shfl_xor(t1, 32);
        t2 += __shfl_xor(t2, 16); t2 += __shfl_xor(t2, 32);
        t3 += __shfl_xor(t3, 16); t3 += __shfl_xor(t3, 32);
        if (sub == 0) {
            float rj = 1.0f / fmaxf((float)(jb - ja), 1.0f);
            float rk = 1.0f / fmaxf((float)(kb - ka), 1.0f);
            float* o = out + (size_t)n * 64;
            o[m16]      = s0 * rj + t0 * rk;   // col' 4m+nt <-> true col 16nt+m
            o[16 + m16] = s1 * rj + t1 * rk;
            o[32 + m16] = s2 * rj + t2 * rk;
            o[48 + m16] = s3 * rj + t3 * rk;
        }
    }
}

// ============================ launch ============================

extern "C" void kernel_launch(void* const* d_in, const int* in_sizes, int n_in,
                              void* d_out, int out_size, void* d_ws, size_t ws_size,
                              hipStream_t stream) {
    (void)in_sizes; (void)n_in; (void)out_size;

    const float* x     = (const float*)d_in[0];
    const float* pos   = (const float*)d_in[1];
    const int*   qidx  = (const int*)d_in[2];
    const float* qattr = (const float*)d_in[3];
    const float* gamma = (const float*)d_in[4];
    const float* beta  = (const float*)d_in[5];
    const float* w1    = (const float*)d_in[6];
    const float* b1    = (const float*)d_in[7];
    const float* w2    = (const float*)d_in[8];
    const float* b2    = (const float*)d_in[9];
    const float* w3    = (const float*)d_in[10];
    const float* b3    = (const float*)d_in[11];
    const float* w_out = (const float*)d_in[12];
    float* out = (float*)d_out;

    size_t o = 0;
    auto alloc = [&](size_t bytes) { size_t r = o; o = (o + bytes + 255) & ~(size_t)255; return r; };
    char* W = (char*)d_ws;
    f16*    msg    = (f16*)   (W + alloc((size_t)2 * ND * 64 * sizeof(f16)));   // 244 MiB
    int*    off    = (int*)   (W + alloc((size_t)NCNT * sizeof(int)));
    int*    bsum   = (int*)   (W + alloc((size_t)NBLK_SCAN * sizeof(int)));
    float2* sqt    = (float2*)(W + alloc((size_t)NN * sizeof(float2)));
    __bf16* w1h    = (__bf16*)(W + alloc((size_t)64 * K1P * sizeof(__bf16)));
    __bf16* w1l    = (__bf16*)(W + alloc((size_t)64 * K1P * sizeof(__bf16)));
    __bf16* w2h    = (__bf16*)(W + alloc((size_t)64 * 64 * sizeof(__bf16)));
    __bf16* w2l    = (__bf16*)(W + alloc((size_t)64 * 64 * sizeof(__bf16)));
    __bf16* w3h    = (__bf16*)(W + alloc((size_t)64 * 64 * sizeof(__bf16)));
    __bf16* w3l    = (__bf16*)(W + alloc((size_t)64 * 64 * sizeof(__bf16)));
    float*  c1     = (float*) (W + alloc((size_t)64 * sizeof(float)));
    float*  d1     = (float*) (W + alloc((size_t)64 * sizeof(float)));
    float*  b3f    = (float*) (W + alloc((size_t)64 * sizeof(float)));
    if (ws_size < o) return;   // ~245 MiB — well within proven ws bound

    // zero histogram, then merged prep (weights + stats + count in ONE launch)
    hipMemsetAsync(off, 0, (size_t)NCNT * sizeof(int), stream);
    prep_merged<<<58 + NBLK_X + NBLK_E, 256, 0, stream>>>(
        x, w1, b1, w2, w3, b3, w_out, gamma, beta, qidx,
        w1h, w1l, c1, d1, w2h, w2l, w3h, w3l, b3f, sqt, off);

    // 3-dispatch scan (R12-proven): off -> global bucket start cursors
    scan1<<<NBLK_SCAN, 256, 0, stream>>>(off, bsum);
    scan2<<<1, 128, 0, stream>>>(bsum);
    scan3<<<NBLK_SCAN, 256, 0, stream>>>(off, bsum);

    // edge MLP (64 edges/wave): acquires slots via atomics on off, dual scatter
    edge_mlp_mfma<<<(ND / 64 + 3) / 4, 256, 0, stream>>>(
        x, sqt, pos, qidx, qattr, w1h, w1l, c1, d1,
        w2h, w2l, b2, w3h, w3l, b3f, off, msg);

    // node aggregation (off now holds bucket ends)
    node_out<<<4096, 256, 0, stream>>>(msg, off, out);
}